// Round 1
// 321.211 us; speedup vs baseline: 1.0144x; 1.0144x over previous
//
#include <hip/hip_runtime.h>

// LSTM B=4096 T=336 I=21 H=50 OUT=24, fp32 in/out.
// Round 9: break the phase convoy + cheaper pointwise.
//   - 256 wgs x 512 thr = 8 waves x 2 M-tiles each (M padded to 256).
//     Each wave's step stream = 12 MFMA (4 indep 3-chains) + 2 cells of
//     pointwise -> MFMA and VALU/trans pipes overlap within/across waves
//     instead of convoying across 13 lockstep waves. Barrier syncs 8 waves.
//   - exp2 folding: gate rows i,f,o pre-scaled by -log2e, g rows by
//     +2*log2e (biases too). sigmoid = rcp(1+exp2(g)), tanh = 1-2*rcp(1+
//     exp2(g)) -> no per-step mul before v_exp. ~23 VALU / 8 trans per cell
//     (was ~31 / 10). Exact reparameterization: scale in fp32, then 2-limb
//     fp16 split -> same 22-bit effective weight precision.
//   - Pad tiles (units 50..63) have zero weights+bias -> h computes to
//     exactly 0 -> pointwise + h-write run unguarded (no divergence),
//     pad slots in hbuf stay 0.
//   - Numerics otherwise unchanged (R6): activations single fp16 in LDS;
//     weights 2 fp16 limbs in VGPRs; gates = Wh.B + Wl.B.
//   - x staged per chunk of CH=12 steps into double-buffered LDS in MFMA
//     B-layout (R8). Global loads only on step 0 of each chunk, issued
//     right after the barrier; steps 1..11 have no outstanding vmem.
// LDS layouts (halves), conflict-free B-frag reads (const + lane*16B):
//   hbuf[buf2][kb8][col16][8]   : h, k=0..63 (units 0..49 valid, rest 0)
//   xC[buf2][s12][kb4][col16][8]: x, k=64..95 (i=k-64 < 21 valid, rest 0)
// Packed gate row = unit*4 + gate -> lane's 4 acc regs = 4 gates of one
// unit; pointwise LSTM update fully in registers.

#define T_SEQ 336
#define I_IN  21
#define HID   50
#define O_OUT 24
#define MB    16
#define NT    512
#define TPW   2                      // tiles per wave (8 waves -> 16 tiles)
#define CH    12
#define NCH   28                     // 336 / 12
#define XELEM (CH * MB * I_IN)       // 4032 floats per chunk
#define NLD   8                      // ceil(4032 / 512)
#define XBUFH (CH * 4 * 16 * 8)      // 6144 halves per x chunk buffer

#define HIDX(buf, kb, n, j) ((((buf)*8 + (kb))*16 + (n))*8 + (j))
#define XIDX(s, kb, n, j)   ((((s)*4 + (kb))*16 + (n))*8 + (j))

#define K_LOG2E 1.44269504088896340736f

typedef _Float16 f16x8 __attribute__((ext_vector_type(8)));
typedef float    f32x4 __attribute__((ext_vector_type(4)));

static __device__ __forceinline__ float frcp(float v) { return __builtin_amdgcn_rcpf(v); }
static __device__ __forceinline__ float ex2(float v)  { return __builtin_amdgcn_exp2f(v); }
// g pre-scaled by -log2e:   sigmoid(v) = rcp(1 + exp2(g))
static __device__ __forceinline__ float sigm2(float g) { return frcp(1.f + ex2(g)); }
// g pre-scaled by +2*log2e: tanh(v) = 1 - 2*rcp(1 + exp2(g))
// overflow -> inf -> rcp -> 0 -> +1; underflow -> exp2->0 -> 1-2*1 = -1 (correct)
static __device__ __forceinline__ float tanh2(float g) {
    return __builtin_fmaf(-2.f, frcp(1.f + ex2(g)), 1.f);
}

__global__ __launch_bounds__(NT)
void lstm_mfma9(const float* __restrict__ x,
                const float* __restrict__ W_ih,
                const float* __restrict__ W_hh,
                const float* __restrict__ b_ih,
                const float* __restrict__ b_hh,
                const float* __restrict__ W_fc,
                const float* __restrict__ b_fc,
                float* __restrict__ out)
{
    __shared__ _Float16 hbuf[2 * 8 * 16 * 8];   // 2048 halves = 4 KB
    __shared__ _Float16 xC[2 * XBUFH];          // 12288 halves = 24 KB

    const int tid  = threadIdx.x;
    const int lane = tid & 63;
    const int wv   = tid >> 6;        // 0..7
    const int nl   = lane & 15;       // A: row-in-tile / B: batch col
    const int q    = lane >> 4;       // quad
    const int b0   = blockIdx.x * MB;

    // ---- zero-init LDS (pads must stay 0 forever; h(0)=0) ----
    for (int i = tid; i < 2 * 8 * 16 * 8; i += NT) hbuf[i] = (_Float16)0.f;
    for (int i = tid; i < 2 * XBUFH;      i += NT) xC[i]   = (_Float16)0.f;

    // ---- x staging precompute + issue chunk-0 loads (drained at barrier) ----
    // element e = tid + k*NT of a chunk: e = ((sI*16)+b)*21 + i
    const float* px[NLD];
    int  xdst[NLD];
    bool xv[NLD];
    float sv[NLD];
    #pragma unroll
    for (int k = 0; k < NLD; ++k) {
        const int e  = tid + k * NT;
        const int i  = e % I_IN;
        const int r  = e / I_IN;
        const int b  = r & 15;
        const int sI = r >> 4;
        xv[k]   = (e < XELEM);
        px[k]   = x + ((size_t)(b0 + b) * T_SEQ + sI) * I_IN + i;
        xdst[k] = XIDX(sI, i >> 3, b, i & 7);
        sv[k]   = px[k][0];            // chunk 0 (loads overlap weight build)
    }

    // ---- A (weight) 2-limb fp16 fragments + bias, built once, pre-scaled ----
    // A[m=nl][k = kc*32 + q*8 + j]; packed row p = t*16+nl -> unit=p>>2, gate=p&3
    // gate scale: i,f,o -> -log2e ; g -> +2*log2e (exp2 folding)
    f16x8 Wh[TPW][3], Wl[TPW][3];
    f32x4 biasv[TPW];
    #pragma unroll
    for (int tt = 0; tt < TPW; ++tt) {
        const int t    = wv * TPW + tt;
        const int p    = t * 16 + nl;
        const int unit = p >> 2, gate = p & 3;
        const bool vr  = (unit < HID);
        const float ws = (gate == 2) ? (2.f * K_LOG2E) : (-K_LOG2E);
        const int orig = gate * HID + unit;       // i,f,g,o stacked row
        const int ub   = t * 4 + q;               // unit for D rows q*4+r
        #pragma unroll
        for (int r = 0; r < 4; ++r) {
            const float bs = (r == 2) ? (2.f * K_LOG2E) : (-K_LOG2E);
            biasv[tt][r] = (ub < HID) ? (b_ih[r * HID + ub] + b_hh[r * HID + ub]) * bs : 0.f;
        }
        #pragma unroll
        for (int kc = 0; kc < 3; ++kc) {
            #pragma unroll
            for (int j = 0; j < 8; ++j) {
                const int k = kc * 32 + q * 8 + j;
                float w = 0.f;
                if (vr) {
                    if (k < 64) { if (k < HID) w = W_hh[orig * HID + k]; }
                    else { const int ki = k - 64; if (ki < I_IN) w = W_ih[orig * I_IN + ki]; }
                }
                w *= ws;
                const _Float16 hi = (_Float16)w;
                Wh[tt][kc][j] = hi;
                Wl[tt][kc][j] = (_Float16)(w - (float)hi);
            }
        }
    }

    __syncthreads();   // zero-init visible (chunk-0 loads drained here too)

    // ---- commit chunk 0 into xC buf 0; advance pointers to chunk 1 ----
    #pragma unroll
    for (int k = 0; k < NLD; ++k) {
        if (xv[k]) xC[xdst[k]] = (_Float16)sv[k];
        px[k] += CH * I_IN;
    }

    // pointwise: lane owns units u0,u1 = (2wv+tt)*4+q for batch nl (c in regs)
    const int u0 = (wv * TPW + 0) * 4 + q;
    const int u1 = (wv * TPW + 1) * 4 + q;
    const int hwo0 = ((u0 >> 3) * 16 + nl) * 8 + (u0 & 7);   // + buf*1024
    const int hwo1 = ((u1 >> 3) * 16 + nl) * 8 + (u1 & 7);
    float cst0 = 0.f, cst1 = 0.f;

    const _Float16* hb0 = &hbuf[HIDX(0, q, nl, 0)];
    const int bfo = ((q * 16) + nl) * 8;           // x B-frag offset within step

    for (int c = 0; c < NCH; ++c) {
        const int  rb    = (c & 1) * XBUFH;
        const int  wb    = ((c + 1) & 1) * XBUFH;
        const bool dostg = (c + 1) < NCH;
        #pragma unroll 2
        for (int s = 0; s < CH; ++s) {
            __syncthreads();   // hbuf[cur] (h) complete; xC[rb] chunk staged

            // staging loads for next chunk: first thing after the barrier
            // (max slack before this step's closing drain)
            if (s == 0 && dostg) {
                #pragma unroll
                for (int k = 0; k < NLD; ++k) sv[k] = px[k][0];
            }

            const int cur = s & 1, nxt = cur ^ 1;

            // ---- B (activation) fragments: 3 contiguous b128 reads, shared
            //      by both of this wave's tiles ----
            const _Float16* hb = hb0 + cur * 1024;
            const f16x8 B0 = *(const f16x8*)(hb);
            const f16x8 B1 = *(const f16x8*)(hb + 4 * 16 * 8);
            const f16x8 B2 = *(const f16x8*)&xC[rb + s * 512 + bfo];

            // ---- MFMA: 4 independent 3-deep chains (2 tiles x hi/lo limb) ----
            f32x4 aA0 = biasv[0];
            f32x4 aB0 = {0.f, 0.f, 0.f, 0.f};
            f32x4 aA1 = biasv[1];
            f32x4 aB1 = {0.f, 0.f, 0.f, 0.f};
            aA0 = __builtin_amdgcn_mfma_f32_16x16x32_f16(Wh[0][0], B0, aA0, 0, 0, 0);
            aA1 = __builtin_amdgcn_mfma_f32_16x16x32_f16(Wh[1][0], B0, aA1, 0, 0, 0);
            aB0 = __builtin_amdgcn_mfma_f32_16x16x32_f16(Wl[0][0], B0, aB0, 0, 0, 0);
            aB1 = __builtin_amdgcn_mfma_f32_16x16x32_f16(Wl[1][0], B0, aB1, 0, 0, 0);
            aA0 = __builtin_amdgcn_mfma_f32_16x16x32_f16(Wh[0][1], B1, aA0, 0, 0, 0);
            aA1 = __builtin_amdgcn_mfma_f32_16x16x32_f16(Wh[1][1], B1, aA1, 0, 0, 0);
            aB0 = __builtin_amdgcn_mfma_f32_16x16x32_f16(Wl[0][1], B1, aB0, 0, 0, 0);
            aB1 = __builtin_amdgcn_mfma_f32_16x16x32_f16(Wl[1][1], B1, aB1, 0, 0, 0);
            aA0 = __builtin_amdgcn_mfma_f32_16x16x32_f16(Wh[0][2], B2, aA0, 0, 0, 0);
            aA1 = __builtin_amdgcn_mfma_f32_16x16x32_f16(Wh[1][2], B2, aA1, 0, 0, 0);
            aB0 = __builtin_amdgcn_mfma_f32_16x16x32_f16(Wl[0][2], B2, aB0, 0, 0, 0);
            aB1 = __builtin_amdgcn_mfma_f32_16x16x32_f16(Wl[1][2], B2, aB1, 0, 0, 0);

            // ---- pointwise cell updates, fully in registers, unguarded ----
            // (pad units: weights+bias 0 -> h computes to exactly 0)
            {
                const float gi = aA0[0] + aB0[0];
                const float gf = aA0[1] + aB0[1];
                const float gg = aA0[2] + aB0[2];
                const float go = aA0[3] + aB0[3];
                const float cc = __builtin_fmaf(sigm2(gf), cst0, sigm2(gi) * tanh2(gg));
                cst0 = cc;
                const float h = sigm2(go) * tanh2(2.f * K_LOG2E * cc);
                hbuf[nxt * 1024 + hwo0] = (_Float16)h;
            }
            {
                const float gi = aA1[0] + aB1[0];
                const float gf = aA1[1] + aB1[1];
                const float gg = aA1[2] + aB1[2];
                const float go = aA1[3] + aB1[3];
                const float cc = __builtin_fmaf(sigm2(gf), cst1, sigm2(gi) * tanh2(gg));
                cst1 = cc;
                const float h = sigm2(go) * tanh2(2.f * K_LOG2E * cc);
                hbuf[nxt * 1024 + hwo1] = (_Float16)h;
            }

            // ---- commit staged x(next chunk) into the other x buffer ----
            if (s == 0 && dostg) {
                #pragma unroll
                for (int k = 0; k < NLD; ++k) {
                    if (xv[k]) xC[wb + xdst[k]] = (_Float16)sv[k];
                    px[k] += CH * I_IN;
                }
            }
        }
    }

    __syncthreads();
    // final h: t=335 wrote buf 0
    // ---- FC epilogue: 16*24 = 384 tasks (one-time) ----
    if (tid < MB * O_OUT) {
        const int b = tid / O_OUT, o = tid % O_OUT;
        float a = b_fc[o];
        for (int u = 0; u < HID; ++u) {
            const float hv = (float)hbuf[HIDX(0, u >> 3, b, u & 7)];
            a = __builtin_fmaf(hv, W_fc[o * HID + u], a);
        }
        out[(size_t)(b0 + b) * O_OUT + o] = a;
    }
}

extern "C" void kernel_launch(void* const* d_in, const int* in_sizes, int n_in,
                              void* d_out, int out_size, void* d_ws, size_t ws_size,
                              hipStream_t stream)
{
    const float* x    = (const float*)d_in[0];
    const float* W_ih = (const float*)d_in[1];
    const float* W_hh = (const float*)d_in[2];
    const float* b_ih = (const float*)d_in[3];
    const float* b_hh = (const float*)d_in[4];
    const float* W_fc = (const float*)d_in[5];
    const float* b_fc = (const float*)d_in[6];
    float* out = (float*)d_out;

    lstm_mfma9<<<dim3(4096 / MB), dim3(NT), 0, stream>>>(
        x, W_ih, W_hh, b_ih, b_hh, W_fc, b_fc, out);
}